// Round 23
// baseline (410.074 us; speedup 1.0000x reference)
//
#include <hip/hip_runtime.h>
#include <hip/hip_bf16.h>
#include <math.h>

#define EMBED   256
#define KDIM    512
#define BATCH   256
#define BM      128
#define VOCAB   50000

typedef float  f32x4   __attribute__((ext_vector_type(4)));
typedef __bf16 bf16x8  __attribute__((ext_vector_type(8)));
typedef unsigned short ushort8 __attribute__((ext_vector_type(8)));

__device__ __forceinline__ unsigned short f2h(float f) {
    unsigned int u = __float_as_uint(f);
    u += 0x7FFFu + ((u >> 16) & 1u);
    return (unsigned short)(u >> 16);
}
__device__ __forceinline__ float h2f(unsigned short h) {
    return __uint_as_float(((unsigned int)h) << 16);
}
// async global->LDS, 16B/lane; LDS dest = wave-uniform base + lane*16; global src per-lane
__device__ __forceinline__ void gload16(const void* g, void* l) {
    __builtin_amdgcn_global_load_lds(
        (const __attribute__((address_space(1))) unsigned int*)g,
        (__attribute__((address_space(3))) unsigned int*)l, 16, 0, 0);
}

#define MFMA16(a,b,c) __builtin_amdgcn_mfma_f32_16x16x32_bf16((a),(b),(c),0,0,0)

// ---------------- prep: split(relu(emb)) + split(W) in one dispatch ----------------
__global__ __launch_bounds__(256) void prep_all(const float* __restrict__ emb,
                                                unsigned short* __restrict__ Eh,
                                                unsigned short* __restrict__ El,
                                                const float* __restrict__ W,
                                                unsigned short* __restrict__ Wh,
                                                unsigned short* __restrict__ Wl,
                                                int wprep)
{
    const int bid = blockIdx.x;
    if (bid < 6250) {                       // emb: 12.8M elems, 8/thread
        const size_t base = ((size_t)bid * 256 + threadIdx.x) * 8;
        float v[8];
        *(float4*)&v[0] = *(const float4*)&emb[base];
        *(float4*)&v[4] = *(const float4*)&emb[base + 4];
        ushort8 hs, ls;
        #pragma unroll
        for (int i = 0; i < 8; ++i) {
            const float f = fmaxf(v[i], 0.f);
            const unsigned short h = f2h(f);
            hs[i] = h;
            ls[i] = f2h(f - h2f(h));
        }
        *(ushort8*)&Eh[base] = hs;
        *(ushort8*)&El[base] = ls;
    } else if (wprep) {                     // W: 131072 elems, 1/thread
        const int i = (bid - 6250) * 256 + threadIdx.x;
        const float w = W[i];
        const unsigned short h = f2h(w);
        Wh[i] = h;
        Wl[i] = f2h(w - h2f(h));
    }
}

// ---------------- main tree GEMM (levels 1..3) — round-10 verified structure ----------------
template<int LV1, int WPREP>
__global__ __launch_bounds__(512) void gemm_tree(
    const unsigned short* __restrict__ Xh, const unsigned short* __restrict__ Xl,
    const unsigned short* __restrict__ Wh, const unsigned short* __restrict__ Wl,
    const float*  __restrict__ Wf,
    const float*  __restrict__ bias,
    unsigned short* __restrict__ Yh, unsigned short* __restrict__ Yl,
    const int* __restrict__ tok,
    const unsigned short* __restrict__ Eh, const unsigned short* __restrict__ El)
{
    __shared__ __align__(16) unsigned short AhL[4096], AlL[4096];    // 128 x 32 hi/lo
    __shared__ __align__(16) unsigned short BhL[8192], BlL[8192];    // 256 x 32 hi/lo

    const int tid = threadIdx.x;
    const int wid = tid >> 6;          // 0..7
    const int l   = tid & 63;
    const int q   = l >> 4;
    const int rr  = l & 15;
    const int m0  = blockIdx.x * BM;

    const int waveM = wid >> 2;        // 0..1
    const int waveN = wid & 3;         // 0..3

    int tk0 = 0, tk1 = 0;
    if constexpr (LV1) {
        const int r = m0 + wid * 16 + rr;
        tk0 = tok[2 * r];
        tk1 = tok[2 * r + 1];
    }

    f32x4 acc[4][4] = {};

    for (int t = 0; t < 16; ++t) {
        const int k0   = t << 5;
        const int joff = k0 >> 8;
        const int c    = (k0 & 255) + q * 8;

        if constexpr (LV1) {
            const size_t off = (size_t)(joff ? tk1 : tk0) * EMBED + c;   // per-lane src
            gload16(Eh + off, &AhL[wid * 512]);
            gload16(El + off, &AlL[wid * 512]);
        } else {
            const size_t off = (size_t)(2 * (m0 + wid * 16 + rr) + joff) * EMBED + c;
            gload16(Xh + off, &AhL[wid * 512]);
            gload16(Xl + off, &AlL[wid * 512]);
        }
        #pragma unroll
        for (int g = 0; g < 2; ++g) {
            const int s = wid + g * 8;
            if constexpr (WPREP) {
                const size_t off = (size_t)(s * 16 + rr) * KDIM + k0 + q * 8;
                gload16(Wh + off, &BhL[s * 512]);
                gload16(Wl + off, &BlL[s * 512]);
            } else {
                const float* ws = Wf + (size_t)(s * 16 + rr) * KDIM + k0 + q * 8;
                float v[8];
                *(float4*)&v[0] = *(const float4*)ws;
                *(float4*)&v[4] = *(const float4*)(ws + 4);
                ushort8 hs, ls;
                #pragma unroll
                for (int i = 0; i < 8; ++i) {
                    const unsigned short h = f2h(v[i]);
                    hs[i] = h;
                    ls[i] = f2h(v[i] - h2f(h));
                }
                *(ushort8*)&BhL[s * 512 + l * 8] = hs;
                *(ushort8*)&BlL[s * 512 + l * 8] = ls;
            }
        }

        __syncthreads();

        bf16x8 ah[4], al[4], bh[4], bl[4];
        #pragma unroll
        for (int mi = 0; mi < 4; ++mi) {
            ah[mi] = *(const bf16x8*)&AhL[(waveM * 4 + mi) * 512 + l * 8];
            al[mi] = *(const bf16x8*)&AlL[(waveM * 4 + mi) * 512 + l * 8];
        }
        #pragma unroll
        for (int ni = 0; ni < 4; ++ni) {
            bh[ni] = *(const bf16x8*)&BhL[(waveN * 4 + ni) * 512 + l * 8];
            bl[ni] = *(const bf16x8*)&BlL[(waveN * 4 + ni) * 512 + l * 8];
        }
        #pragma unroll
        for (int mi = 0; mi < 4; ++mi)
            #pragma unroll
            for (int ni = 0; ni < 4; ++ni)
                acc[mi][ni] = MFMA16(ah[mi], bh[ni], acc[mi][ni]);
        #pragma unroll
        for (int mi = 0; mi < 4; ++mi)
            #pragma unroll
            for (int ni = 0; ni < 4; ++ni)
                acc[mi][ni] = MFMA16(al[mi], bh[ni], acc[mi][ni]);
        #pragma unroll
        for (int mi = 0; mi < 4; ++mi)
            #pragma unroll
            for (int ni = 0; ni < 4; ++ni)
                acc[mi][ni] = MFMA16(ah[mi], bl[ni], acc[mi][ni]);

        __syncthreads();
    }

    #pragma unroll
    for (int ni = 0; ni < 4; ++ni) {
        const int col = waveN * 64 + ni * 16 + rr;
        const float bv = bias[col];
        #pragma unroll
        for (int mi = 0; mi < 4; ++mi) {
            const int row0 = m0 + waveM * 64 + mi * 16 + q * 4;
            #pragma unroll
            for (int jj = 0; jj < 4; ++jj) {
                const float y = fmaxf(acc[mi][ni][jj] + bv, 0.f);
                const unsigned short h = f2h(y);
                Yh[(size_t)(row0 + jj) * EMBED + col] = h;
                Yl[(size_t)(row0 + jj) * EMBED + col] = f2h(y - h2f(h));
            }
        }
    }
}

// ---------------- tail4: levels 4..10 + head, 1024 thr / 16 waves, LDS-resident after L4 ----------------
// L4: A staged from L3-out (global), B dbuf staged; OUTPUT -> LDS XL4 (64 rows, swizzled).
// L5: A from XL4 (LDS), direct-reg B, barrier-free loop. L6-10: r22 structure.
// LDS regions phase-unioned in one 144KB array; barriers fence every region handoff.
template<int WPREP>
__global__ __launch_bounds__(1024) void tail4(
    const unsigned short* __restrict__ A3h, const unsigned short* __restrict__ A3l,  // L3 out 32768x256
    const unsigned short* __restrict__ Wh, const unsigned short* __restrict__ Wl,
    const float* __restrict__ Wf, const float* __restrict__ bias,
    const float* __restrict__ Pw, const float* __restrict__ Pb,
    const int* __restrict__ labels, float* __restrict__ out)
{
    __shared__ __align__(16) unsigned char SM[147456];   // 144KB
    // Phase L4:  AhT @0 (2x2048 us), AlT @8K, BhT @16K (2x8192 us), BlT @48K,
    //            XL4h @80K (64x256 us), XL4l @112K
    // Phase L5+: X0h @0 (32x256), X0l @16K, X1h @32K (16x256), X1l @40K
    unsigned short* AhT0 = (unsigned short*)(SM);
    unsigned short* AlT0 = (unsigned short*)(SM + 8192);
    unsigned short* BhT0 = (unsigned short*)(SM + 16384);
    unsigned short* BlT0 = (unsigned short*)(SM + 49152);
    unsigned short* XL4h = (unsigned short*)(SM + 81920);
    unsigned short* XL4l = (unsigned short*)(SM + 114688);
    unsigned short* X0h  = (unsigned short*)(SM);
    unsigned short* X0l  = (unsigned short*)(SM + 16384);
    unsigned short* X1h  = (unsigned short*)(SM + 32768);
    unsigned short* X1l  = (unsigned short*)(SM + 40960);

    const int tid = threadIdx.x;
    const int w   = tid >> 6;      // 0..15
    const int l   = tid & 63;
    const int q   = l >> 4;
    const int rr  = l & 15;
    const int b   = blockIdx.x;

    auto stageB = [&](int buf, int k0) {
        if constexpr (WPREP) {
            #pragma unroll
            for (int j = 0; j < 2; ++j) {
                const int sb = w * 2 + j;          // 0..31
                const int s  = sb & 15;
                const size_t off = (size_t)(s * 16 + rr) * KDIM + k0 + q * 8;
                if (sb < 16) gload16(Wh + off, &BhT0[buf * 8192 + s * 512]);
                else         gload16(Wl + off, &BlT0[buf * 8192 + s * 512]);
            }
        } else {
            const int u = w;                       // 0..15
            const float* ws = Wf + (size_t)(u * 16 + rr) * KDIM + k0 + q * 8;
            float v[8];
            *(float4*)&v[0] = *(const float4*)ws;
            *(float4*)&v[4] = *(const float4*)(ws + 4);
            ushort8 hs, ls;
            #pragma unroll
            for (int i = 0; i < 8; ++i) {
                const unsigned short h = f2h(v[i]);
                hs[i] = h;
                ls[i] = f2h(v[i] - h2f(h));
            }
            *(ushort8*)&BhT0[buf * 8192 + u * 512 + l * 8] = hs;
            *(ushort8*)&BlT0[buf * 8192 + u * 512 + l * 8] = ls;
        }
    };

    // =================== L4: A3 window [128b..128b+128) -> XL4 (64 rows, LDS swz) ===================
    {
        const int waveM = w >> 2;      // 0..3 -> out rows waveM*16..
        const int waveN = w & 3;       // 0..3 -> cols waveN*64..
        float bv4[4];
        #pragma unroll
        for (int ni = 0; ni < 4; ++ni) bv4[ni] = bias[waveN * 64 + ni * 16 + rr];

        auto stageA4 = [&](int buf, int t) {   // waves 0-3 hi, 4-7 lo; subtile s = w&3
            if (w < 8) {
                const int k0 = t * 32, joff = t >> 3, c = (k0 & 255) + q * 8;
                const int s = w & 3;
                const size_t off = (size_t)(128 * b + 2 * (s * 16 + rr) + joff) * EMBED + c;
                if (w < 4) gload16(A3h + off, &AhT0[buf * 2048 + s * 512]);
                else       gload16(A3l + off, &AlT0[buf * 2048 + s * 512]);
            }
        };

        stageB(0, 0);
        stageA4(0, 0);
        __syncthreads();

        f32x4 acc[4] = {};     // 4 N-frags, wave tile 16 x 64
        for (int t = 0; t < 16; ++t) {
            const int cur = t & 1;
            if (t < 15) { stageB(cur ^ 1, (t + 1) * 32); stageA4(cur ^ 1, t + 1); }

            const bf16x8 a_h = *(const bf16x8*)&AhT0[cur * 2048 + waveM * 512 + l * 8];
            const bf16x8 a_l = *(const bf16x8*)&AlT0[cur * 2048 + waveM * 512 + l * 8];
            bf16x8 bh[4], bl[4];
            #pragma unroll
            for (int ni = 0; ni < 4; ++ni) {
                bh[ni] = *(const bf16x8*)&BhT0[cur * 8192 + (waveN * 4 + ni) * 512 + l * 8];
                bl[ni] = *(const bf16x8*)&BlT0[cur * 8192 + (waveN * 4 + ni) * 512 + l * 8];
            }
            #pragma unroll
            for (int ni = 0; ni < 4; ++ni) acc[ni] = MFMA16(a_h, bh[ni], acc[ni]);
            #pragma unroll
            for (int ni = 0; ni < 4; ++ni) acc[ni] = MFMA16(a_l, bh[ni], acc[ni]);
            #pragma unroll
            for (int ni = 0; ni < 4; ++ni) acc[ni] = MFMA16(a_h, bl[ni], acc[ni]);

            __syncthreads();
        }
        // epilogue -> XL4 (swizzled); out rows 0..63
        #pragma unroll
        for (int ni = 0; ni < 4; ++ni) {
            const int col = waveN * 64 + ni * 16 + rr;
            #pragma unroll
            for (int jj = 0; jj < 4; ++jj) {
                const int row = waveM * 16 + q * 4 + jj;
                const float y = fmaxf(acc[ni][jj] + bv4[ni], 0.f);
                const unsigned short h = f2h(y);
                const int idx = (row * 256 + col) ^ ((row & 7) << 3);
                XL4h[idx] = h;
                XL4l[idx] = f2h(y - h2f(h));
            }
        }
    }
    __syncthreads();   // XL4 complete; A/B dbuf regions now dead (reused below)

    // =================== L5: XL4 (LDS) -> X0 (32 rows, swz); direct-reg B ===================
    {
        const int waveM = w >> 3;      // 0..1
        const int waveN = w & 7;       // 0..7 -> 32-col slice
        float bv2[2];
        #pragma unroll
        for (int ni = 0; ni < 2; ++ni) bv2[ni] = bias[waveN * 32 + ni * 16 + rr];

        f32x4 acc[2] = {};
        #pragma unroll
        for (int t = 0; t < 16; ++t) {
            const int k0 = t * 32, joff = t >> 3, c = (k0 & 255) + q * 8;
            const int row = 2 * (waveM * 16 + rr) + joff;   // 0..63
            const int idx = (row * 256 + c) ^ ((row & 7) << 3);
            const bf16x8 a_h = *(const bf16x8*)&XL4h[idx];
            const bf16x8 a_l = *(const bf16x8*)&XL4l[idx];

            bf16x8 bh[2], bl[2];
            #pragma unroll
            for (int ni = 0; ni < 2; ++ni) {
                const size_t off = (size_t)(waveN * 32 + ni * 16 + rr) * KDIM + k0 + q * 8;
                if constexpr (WPREP) {
                    bh[ni] = *(const bf16x8*)&Wh[off];
                    bl[ni] = *(const bf16x8*)&Wl[off];
                } else {
                    const float* ws = Wf + off;
                    float v[8];
                    *(float4*)&v[0] = *(const float4*)ws;
                    *(float4*)&v[4] = *(const float4*)(ws + 4);
                    ushort8 hs, ls;
                    #pragma unroll
                    for (int i = 0; i < 8; ++i) {
                        const unsigned short h = f2h(v[i]);
                        hs[i] = h;
                        ls[i] = f2h(v[i] - h2f(h));
                    }
                    bh[ni] = __builtin_bit_cast(bf16x8, hs);
                    bl[ni] = __builtin_bit_cast(bf16x8, ls);
                }
            }
            #pragma unroll
            for (int ni = 0; ni < 2; ++ni) acc[ni] = MFMA16(a_h, bh[ni], acc[ni]);
            #pragma unroll
            for (int ni = 0; ni < 2; ++ni) acc[ni] = MFMA16(a_l, bh[ni], acc[ni]);
            #pragma unroll
            for (int ni = 0; ni < 2; ++ni) acc[ni] = MFMA16(a_h, bl[ni], acc[ni]);
        }
        // epilogue -> X0 (region-reuse of dead A/B dbuf; fenced by barriers)
        #pragma unroll
        for (int ni = 0; ni < 2; ++ni) {
            const int col = waveN * 32 + ni * 16 + rr;
            #pragma unroll
            for (int jj = 0; jj < 4; ++jj) {
                const int row = waveM * 16 + q * 4 + jj;   // 0..31
                const float y = fmaxf(acc[ni][jj] + bv2[ni], 0.f);
                const unsigned short h = f2h(y);
                const int idx = (row * 256 + col) ^ ((row & 7) << 3);
                X0h[idx] = h;
                X0l[idx] = f2h(y - h2f(h));
            }
        }
    }
    __syncthreads();

    // ===== L6..L10: barrier-free direct-register B (16-way N split); A from LDS ping-pong =====
    const float bv1 = bias[w * 16 + rr];

    for (int s = 0; s < 5; ++s) {
        const unsigned short* srch = (s & 1) ? X1h : X0h;
        const unsigned short* srcl = (s & 1) ? X1l : X0l;
        unsigned short* dsth = (s & 1) ? X0h : X1h;
        unsigned short* dstl = (s & 1) ? X0l : X1l;
        const int mask = (s & 1) ? 15 : 31;
        const int Mout = 16 >> s;

        f32x4 acc = {};
        #pragma unroll
        for (int t = 0; t < 16; ++t) {
            const int k0 = t * 32, joff = t >> 3, c = (k0 & 255) + q * 8;
            const int row = (2 * rr + joff) & mask;
            const int idx = (row * 256 + c) ^ ((row & 7) << 3);
            const bf16x8 a_h = *(const bf16x8*)&srch[idx];
            const bf16x8 a_l = *(const bf16x8*)&srcl[idx];

            bf16x8 bh, bl;
            {
                const size_t off = (size_t)(w * 16 + rr) * KDIM + k0 + q * 8;
                if constexpr (WPREP) {
                    bh = *(const bf16x8*)&Wh[off];
                    bl = *(const bf16x8*)&Wl[off];
                } else {
                    const float* ws = Wf + off;
                    float v[8];
                    *(float4*)&v[0] = *(const float4*)ws;
                    *(float4*)&v[4] = *(const float4*)(ws + 4);
                    ushort8 hs, ls;
                    #pragma unroll
                    for (int i = 0; i < 8; ++i) {
                        const unsigned short h = f2h(v[i]);
                        hs[i] = h;
                        ls[i] = f2h(v[i] - h2f(h));
                    }
                    bh = __builtin_bit_cast(bf16x8, hs);
                    bl = __builtin_bit_cast(bf16x8, ls);
                }
            }
            acc = MFMA16(a_h, bh, acc);
            acc = MFMA16(a_l, bh, acc);
            acc = MFMA16(a_h, bl, acc);
        }

        {
            const int col = w * 16 + rr;
            #pragma unroll
            for (int jj = 0; jj < 4; ++jj) {
                const int row = q * 4 + jj;
                if (row < Mout) {
                    const float y = fmaxf(acc[jj] + bv1, 0.f);
                    const unsigned short h = f2h(y);
                    const int idx = (row * 256 + col) ^ ((row & 7) << 3);
                    dsth[idx] = h;
                    dstl[idx] = f2h(y - h2f(h));
                }
            }
        }
        __syncthreads();   // dst complete before next level reads it
    }

    // head: root = X1 row 0 (L10 dst = X1; swizzle identity for row 0)
    if (w == 0) {
        float s0 = 0.f, s1 = 0.f;
        #pragma unroll
        for (int i = 0; i < 4; ++i) {
            const int col = l + i * 64;
            const float x = h2f(X1h[col]) + h2f(X1l[col]);
            s0 = fmaf(x, Pw[col], s0);
            s1 = fmaf(x, Pw[EMBED + col], s1);
        }
        #pragma unroll
        for (int off = 32; off > 0; off >>= 1) {
            s0 += __shfl_down(s0, off);
            s1 += __shfl_down(s1, off);
        }
        if (l == 0) {
            const float l0 = s0 + Pb[0];
            const float l1 = s1 + Pb[1];
            const int pred = (l1 > l0) ? 1 : 0;
            const float m  = fmaxf(l0, l1);
            const float lse = m + logf(expf(l0 - m) + expf(l1 - m));
            const int lab = labels[b];
            out[b]         = (float)pred;
            out[BATCH + b] = lse - (lab ? l1 : l0);
        }
    }
}

extern "C" void kernel_launch(void* const* d_in, const int* in_sizes, int n_in,
                              void* d_out, int out_size, void* d_ws, size_t ws_size,
                              hipStream_t stream)
{
    const int*   token_ids = (const int*)d_in[0];
    const int*   labels    = (const int*)d_in[1];
    const float* emb       = (const float*)d_in[2];
    const float* W_w       = (const float*)d_in[3];
    const float* W_b       = (const float*)d_in[4];
    const float* P_w       = (const float*)d_in[5];
    const float* P_b       = (const float*)d_in[6];
    float*       out       = (float*)d_out;

    // ws layout (ushort units):
    //   Ah/Al: L1 out (131072x256); L3 overwrites with its out (32768x256) — L1 out dead after L2
    //   Bh/Bl: L2 out (65536x256); hosts pre-split emb tables Eh/El during L1
    //   Wh/Wl: split weights
    unsigned short* Ah_buf = (unsigned short*)d_ws;
    unsigned short* Al_buf = Ah_buf + (size_t)131072 * 256;
    unsigned short* Bh_buf = Al_buf + (size_t)131072 * 256;
    unsigned short* Bl_buf = Bh_buf + (size_t)65536 * 256;
    unsigned short* Wh     = Bl_buf + (size_t)65536 * 256;
    unsigned short* Wl     = Wh + 131072;
    unsigned short* Eh     = Bh_buf;
    unsigned short* El     = Bl_buf;

    const size_t need_wprep = ((size_t)131072 * 256 * 2 + (size_t)65536 * 256 * 2 + 2 * 131072) * 2;
    const bool wprep = ws_size >= need_wprep;

    prep_all<<<6762, 256, 0, stream>>>(emb, Eh, El, W_w, Wh, Wl, wprep ? 1 : 0);

    if (wprep) {
        gemm_tree<1,1><<<1024, 512, 0, stream>>>(nullptr, nullptr, Wh, Wl, W_w, W_b, Ah_buf, Al_buf, token_ids, Eh, El);
        gemm_tree<0,1><<< 512, 512, 0, stream>>>(Ah_buf, Al_buf, Wh, Wl, W_w, W_b, Bh_buf, Bl_buf, nullptr, nullptr, nullptr);
        gemm_tree<0,1><<< 256, 512, 0, stream>>>(Bh_buf, Bl_buf, Wh, Wl, W_w, W_b, Ah_buf, Al_buf, nullptr, nullptr, nullptr);
        tail4<1><<<BATCH, 1024, 0, stream>>>(Ah_buf, Al_buf, Wh, Wl, W_w, W_b, P_w, P_b, labels, out);
    } else {
        gemm_tree<1,0><<<1024, 512, 0, stream>>>(nullptr, nullptr, Wh, Wl, W_w, W_b, Ah_buf, Al_buf, token_ids, Eh, El);
        gemm_tree<0,0><<< 512, 512, 0, stream>>>(Ah_buf, Al_buf, Wh, Wl, W_w, W_b, Bh_buf, Bl_buf, nullptr, nullptr, nullptr);
        gemm_tree<0,0><<< 256, 512, 0, stream>>>(Bh_buf, Bl_buf, Wh, Wl, W_w, W_b, Ah_buf, Al_buf, nullptr, nullptr, nullptr);
        tail4<0><<<BATCH, 1024, 0, stream>>>(Ah_buf, Al_buf, Wh, Wl, W_w, W_b, P_w, P_b, labels, out);
    }
}

// Round 24
// 381.589 us; speedup vs baseline: 1.0746x; 1.0746x over previous
//
#include <hip/hip_runtime.h>
#include <hip/hip_bf16.h>
#include <math.h>

#define EMBED   256
#define KDIM    512
#define BATCH   256
#define BM      128
#define VOCAB   50000

typedef float  f32x4   __attribute__((ext_vector_type(4)));
typedef __bf16 bf16x8  __attribute__((ext_vector_type(8)));
typedef unsigned short ushort8 __attribute__((ext_vector_type(8)));

__device__ __forceinline__ unsigned short f2h(float f) {
    unsigned int u = __float_as_uint(f);
    u += 0x7FFFu + ((u >> 16) & 1u);
    return (unsigned short)(u >> 16);
}
__device__ __forceinline__ float h2f(unsigned short h) {
    return __uint_as_float(((unsigned int)h) << 16);
}
// async global->LDS, 16B/lane; LDS dest = wave-uniform base + lane*16; global src per-lane
__device__ __forceinline__ void gload16(const void* g, void* l) {
    __builtin_amdgcn_global_load_lds(
        (const __attribute__((address_space(1))) unsigned int*)g,
        (__attribute__((address_space(3))) unsigned int*)l, 16, 0, 0);
}

#define MFMA16(a,b,c) __builtin_amdgcn_mfma_f32_16x16x32_bf16((a),(b),(c),0,0,0)

// ---------------- prep: split(relu(emb)) + split(W) in one dispatch ----------------
__global__ __launch_bounds__(256) void prep_all(const float* __restrict__ emb,
                                                unsigned short* __restrict__ Eh,
                                                unsigned short* __restrict__ El,
                                                const float* __restrict__ W,
                                                unsigned short* __restrict__ Wh,
                                                unsigned short* __restrict__ Wl,
                                                int wprep)
{
    const int bid = blockIdx.x;
    if (bid < 6250) {                       // emb: 12.8M elems, 8/thread
        const size_t base = ((size_t)bid * 256 + threadIdx.x) * 8;
        float v[8];
        *(float4*)&v[0] = *(const float4*)&emb[base];
        *(float4*)&v[4] = *(const float4*)&emb[base + 4];
        ushort8 hs, ls;
        #pragma unroll
        for (int i = 0; i < 8; ++i) {
            const float f = fmaxf(v[i], 0.f);
            const unsigned short h = f2h(f);
            hs[i] = h;
            ls[i] = f2h(f - h2f(h));
        }
        *(ushort8*)&Eh[base] = hs;
        *(ushort8*)&El[base] = ls;
    } else if (wprep) {                     // W: 131072 elems, 1/thread
        const int i = (bid - 6250) * 256 + threadIdx.x;
        const float w = W[i];
        const unsigned short h = f2h(w);
        Wh[i] = h;
        Wl[i] = f2h(w - h2f(h));
    }
}

// ---------------- main tree GEMM (levels 1..2) — round-10 verified structure ----------------
template<int LV1, int WPREP>
__global__ __launch_bounds__(512) void gemm_tree(
    const unsigned short* __restrict__ Xh, const unsigned short* __restrict__ Xl,
    const unsigned short* __restrict__ Wh, const unsigned short* __restrict__ Wl,
    const float*  __restrict__ Wf,
    const float*  __restrict__ bias,
    unsigned short* __restrict__ Yh, unsigned short* __restrict__ Yl,
    const int* __restrict__ tok,
    const unsigned short* __restrict__ Eh, const unsigned short* __restrict__ El)
{
    __shared__ __align__(16) unsigned short AhL[4096], AlL[4096];    // 128 x 32 hi/lo
    __shared__ __align__(16) unsigned short BhL[8192], BlL[8192];    // 256 x 32 hi/lo

    const int tid = threadIdx.x;
    const int wid = tid >> 6;          // 0..7
    const int l   = tid & 63;
    const int q   = l >> 4;
    const int rr  = l & 15;
    const int m0  = blockIdx.x * BM;

    const int waveM = wid >> 2;        // 0..1
    const int waveN = wid & 3;         // 0..3

    int tk0 = 0, tk1 = 0;
    if constexpr (LV1) {
        const int r = m0 + wid * 16 + rr;
        tk0 = tok[2 * r];
        tk1 = tok[2 * r + 1];
    }

    f32x4 acc[4][4] = {};

    for (int t = 0; t < 16; ++t) {
        const int k0   = t << 5;
        const int joff = k0 >> 8;
        const int c    = (k0 & 255) + q * 8;

        if constexpr (LV1) {
            const size_t off = (size_t)(joff ? tk1 : tk0) * EMBED + c;   // per-lane src
            gload16(Eh + off, &AhL[wid * 512]);
            gload16(El + off, &AlL[wid * 512]);
        } else {
            const size_t off = (size_t)(2 * (m0 + wid * 16 + rr) + joff) * EMBED + c;
            gload16(Xh + off, &AhL[wid * 512]);
            gload16(Xl + off, &AlL[wid * 512]);
        }
        #pragma unroll
        for (int g = 0; g < 2; ++g) {
            const int s = wid + g * 8;
            if constexpr (WPREP) {
                const size_t off = (size_t)(s * 16 + rr) * KDIM + k0 + q * 8;
                gload16(Wh + off, &BhL[s * 512]);
                gload16(Wl + off, &BlL[s * 512]);
            } else {
                const float* ws = Wf + (size_t)(s * 16 + rr) * KDIM + k0 + q * 8;
                float v[8];
                *(float4*)&v[0] = *(const float4*)ws;
                *(float4*)&v[4] = *(const float4*)(ws + 4);
                ushort8 hs, ls;
                #pragma unroll
                for (int i = 0; i < 8; ++i) {
                    const unsigned short h = f2h(v[i]);
                    hs[i] = h;
                    ls[i] = f2h(v[i] - h2f(h));
                }
                *(ushort8*)&BhL[s * 512 + l * 8] = hs;
                *(ushort8*)&BlL[s * 512 + l * 8] = ls;
            }
        }

        __syncthreads();

        bf16x8 ah[4], al[4], bh[4], bl[4];
        #pragma unroll
        for (int mi = 0; mi < 4; ++mi) {
            ah[mi] = *(const bf16x8*)&AhL[(waveM * 4 + mi) * 512 + l * 8];
            al[mi] = *(const bf16x8*)&AlL[(waveM * 4 + mi) * 512 + l * 8];
        }
        #pragma unroll
        for (int ni = 0; ni < 4; ++ni) {
            bh[ni] = *(const bf16x8*)&BhL[(waveN * 4 + ni) * 512 + l * 8];
            bl[ni] = *(const bf16x8*)&BlL[(waveN * 4 + ni) * 512 + l * 8];
        }
        #pragma unroll
        for (int mi = 0; mi < 4; ++mi)
            #pragma unroll
            for (int ni = 0; ni < 4; ++ni)
                acc[mi][ni] = MFMA16(ah[mi], bh[ni], acc[mi][ni]);
        #pragma unroll
        for (int mi = 0; mi < 4; ++mi)
            #pragma unroll
            for (int ni = 0; ni < 4; ++ni)
                acc[mi][ni] = MFMA16(al[mi], bh[ni], acc[mi][ni]);
        #pragma unroll
        for (int mi = 0; mi < 4; ++mi)
            #pragma unroll
            for (int ni = 0; ni < 4; ++ni)
                acc[mi][ni] = MFMA16(ah[mi], bl[ni], acc[mi][ni]);

        __syncthreads();
    }

    #pragma unroll
    for (int ni = 0; ni < 4; ++ni) {
        const int col = waveN * 64 + ni * 16 + rr;
        const float bv = bias[col];
        #pragma unroll
        for (int mi = 0; mi < 4; ++mi) {
            const int row0 = m0 + waveM * 64 + mi * 16 + q * 4;
            #pragma unroll
            for (int jj = 0; jj < 4; ++jj) {
                const float y = fmaxf(acc[mi][ni][jj] + bv, 0.f);
                const unsigned short h = f2h(y);
                Yh[(size_t)(row0 + jj) * EMBED + col] = h;
                Yl[(size_t)(row0 + jj) * EMBED + col] = f2h(y - h2f(h));
            }
        }
    }
}

// ---------------- staged tail: levels 3..10 + head, 1024 thr / 16 waves ----------------
// r22 (best measured): 16 waves = 4 waves/SIMD. Staged L3-L5, barrier-free
// direct-register-B L6-10, head fused.
template<int WPREP>
__global__ __launch_bounds__(1024) void tail3(
    const unsigned short* __restrict__ A2h, const unsigned short* __restrict__ A2l,  // L2 out 65536x256
    unsigned short* __restrict__ S3h, unsigned short* __restrict__ S3l,              // scratch: L3out 32768x256, L4out at +32768*256
    const unsigned short* __restrict__ Wh, const unsigned short* __restrict__ Wl,
    const float* __restrict__ Wf, const float* __restrict__ bias,
    const float* __restrict__ Pw, const float* __restrict__ Pb,
    const int* __restrict__ labels, float* __restrict__ out)
{
    __shared__ __align__(16) unsigned short AhT[2][4096], AlT[2][4096];   // 32KB A dbuf
    __shared__ __align__(16) unsigned short BhT[2][8192], BlT[2][8192];   // 64KB B dbuf
    __shared__ __align__(16) unsigned short X0h[8192], X0l[8192];         // 32 rows swz
    __shared__ __align__(16) unsigned short X1h[4096], X1l[4096];         // 16 rows swz

    const int tid = threadIdx.x;
    const int w   = tid >> 6;      // 0..15
    const int l   = tid & 63;
    const int q   = l >> 4;
    const int rr  = l & 15;
    const int b   = blockIdx.x;

    unsigned short* L4h = S3h + (size_t)32768 * 256;
    unsigned short* L4l = S3l + (size_t)32768 * 256;

    const int waveM = w >> 3;      // 0..1
    const int waveN = w & 7;       // 0..7 -> 32-col slice

    auto stageB = [&](int buf, int k0) {
        if constexpr (WPREP) {
            #pragma unroll
            for (int j = 0; j < 2; ++j) {
                const int sb = w * 2 + j;          // 0..31
                const int s  = sb & 15;
                const size_t off = (size_t)(s * 16 + rr) * KDIM + k0 + q * 8;
                if (sb < 16) gload16(Wh + off, &BhT[buf][s * 512]);
                else         gload16(Wl + off, &BlT[buf][s * 512]);
            }
        } else {
            const int u = w;                       // 0..15
            const float* ws = Wf + (size_t)(u * 16 + rr) * KDIM + k0 + q * 8;
            float v[8];
            *(float4*)&v[0] = *(const float4*)ws;
            *(float4*)&v[4] = *(const float4*)(ws + 4);
            ushort8 hs, ls;
            #pragma unroll
            for (int i = 0; i < 8; ++i) {
                const unsigned short h = f2h(v[i]);
                hs[i] = h;
                ls[i] = f2h(v[i] - h2f(h));
            }
            *(ushort8*)&BhT[buf][u * 512 + l * 8] = hs;
            *(ushort8*)&BlT[buf][u * 512 + l * 8] = ls;
        }
    };

    float bv2[2];
    #pragma unroll
    for (int ni = 0; ni < 2; ++ni) bv2[ni] = bias[waveN * 32 + ni * 16 + rr];

    int g = 0;   // staged-B step counter (L3..L5 = 48 steps)

    // =================== L3: A2 window [256b..256b+256) -> S3 rows [128b..128b+128) ===================
    auto stageA3 = [&](int buf, int t) {     // 16 wave-loads: subtile w&7, w<8 hi else lo
        const int k0 = t * 32, joff = t >> 3, c = (k0 & 255) + q * 8;
        const int s = w & 7;
        const size_t off = (size_t)(256 * b + 2 * (s * 16 + rr) + joff) * EMBED + c;
        if (w < 8) gload16(A2h + off, &AhT[buf][s * 512]);
        else       gload16(A2l + off, &AlT[buf][s * 512]);
    };
    stageB(0, 0);
    stageA3(0, 0);
    __syncthreads();
    {
        f32x4 acc[4][2] = {};
        for (int t = 0; t < 16; ++t, ++g) {
            const int cur = g & 1;
            if (g < 47) stageB(cur ^ 1, ((t + 1) & 15) * 32);
            if (t < 15) stageA3((t + 1) & 1, t + 1);

            bf16x8 ah[4], al[4], bh[2], bl[2];
            #pragma unroll
            for (int mi = 0; mi < 4; ++mi) {
                ah[mi] = *(const bf16x8*)&AhT[t & 1][(waveM * 4 + mi) * 512 + l * 8];
                al[mi] = *(const bf16x8*)&AlT[t & 1][(waveM * 4 + mi) * 512 + l * 8];
            }
            #pragma unroll
            for (int ni = 0; ni < 2; ++ni) {
                bh[ni] = *(const bf16x8*)&BhT[cur][(waveN * 2 + ni) * 512 + l * 8];
                bl[ni] = *(const bf16x8*)&BlT[cur][(waveN * 2 + ni) * 512 + l * 8];
            }
            #pragma unroll
            for (int mi = 0; mi < 4; ++mi)
                #pragma unroll
                for (int ni = 0; ni < 2; ++ni)
                    acc[mi][ni] = MFMA16(ah[mi], bh[ni], acc[mi][ni]);
            #pragma unroll
            for (int mi = 0; mi < 4; ++mi)
                #pragma unroll
                for (int ni = 0; ni < 2; ++ni)
                    acc[mi][ni] = MFMA16(al[mi], bh[ni], acc[mi][ni]);
            #pragma unroll
            for (int mi = 0; mi < 4; ++mi)
                #pragma unroll
                for (int ni = 0; ni < 2; ++ni)
                    acc[mi][ni] = MFMA16(ah[mi], bl[ni], acc[mi][ni]);

            __syncthreads();
        }
        #pragma unroll
        for (int ni = 0; ni < 2; ++ni) {
            const int col = waveN * 32 + ni * 16 + rr;
            #pragma unroll
            for (int mi = 0; mi < 4; ++mi)
                #pragma unroll
                for (int jj = 0; jj < 4; ++jj) {
                    const int row = waveM * 64 + mi * 16 + q * 4 + jj;
                    const float y = fmaxf(acc[mi][ni][jj] + bv2[ni], 0.f);
                    const unsigned short h = f2h(y);
                    S3h[(size_t)(128 * b + row) * EMBED + col] = h;
                    S3l[(size_t)(128 * b + row) * EMBED + col] = f2h(y - h2f(h));
                }
        }
    }
    __syncthreads();   // drains stores -> L4 stage loads see them

    // =================== L4: S3 window [128b..) -> L4 scratch rows [64b..64b+64) ===================
    auto stageA4 = [&](int buf, int t) {     // 8 wave-loads: subtile w&3, w<4 hi else lo
        if (w < 8) {
            const int k0 = t * 32, joff = t >> 3, c = (k0 & 255) + q * 8;
            const int s = w & 3;
            const size_t off = (size_t)(128 * b + 2 * (s * 16 + rr) + joff) * EMBED + c;
            if (w < 4) gload16(S3h + off, &AhT[buf][s * 512]);
            else       gload16(S3l + off, &AlT[buf][s * 512]);
        }
    };
    stageA4(0, 0);
    __syncthreads();   // prologue stage must land before first read
    {
        f32x4 acc[2][2] = {};
        for (int t = 0; t < 16; ++t, ++g) {
            const int cur = g & 1;
            if (g < 47) stageB(cur ^ 1, ((t + 1) & 15) * 32);
            if (t < 15) stageA4((t + 1) & 1, t + 1);

            bf16x8 bh[2], bl[2];
            #pragma unroll
            for (int ni = 0; ni < 2; ++ni) {
                bh[ni] = *(const bf16x8*)&BhT[cur][(waveN * 2 + ni) * 512 + l * 8];
                bl[ni] = *(const bf16x8*)&BlT[cur][(waveN * 2 + ni) * 512 + l * 8];
            }
            #pragma unroll
            for (int mi = 0; mi < 2; ++mi) {
                const bf16x8 a_h = *(const bf16x8*)&AhT[t & 1][(waveM * 2 + mi) * 512 + l * 8];
                const bf16x8 a_l = *(const bf16x8*)&AlT[t & 1][(waveM * 2 + mi) * 512 + l * 8];
                #pragma unroll
                for (int ni = 0; ni < 2; ++ni) acc[mi][ni] = MFMA16(a_h, bh[ni], acc[mi][ni]);
                #pragma unroll
                for (int ni = 0; ni < 2; ++ni) acc[mi][ni] = MFMA16(a_l, bh[ni], acc[mi][ni]);
                #pragma unroll
                for (int ni = 0; ni < 2; ++ni) acc[mi][ni] = MFMA16(a_h, bl[ni], acc[mi][ni]);
            }
            __syncthreads();
        }
        #pragma unroll
        for (int ni = 0; ni < 2; ++ni) {
            const int col = waveN * 32 + ni * 16 + rr;
            #pragma unroll
            for (int mi = 0; mi < 2; ++mi)
                #pragma unroll
                for (int jj = 0; jj < 4; ++jj) {
                    const int row = waveM * 32 + mi * 16 + q * 4 + jj;
                    const float y = fmaxf(acc[mi][ni][jj] + bv2[ni], 0.f);
                    const unsigned short h = f2h(y);
                    L4h[(size_t)(64 * b + row) * EMBED + col] = h;
                    L4l[(size_t)(64 * b + row) * EMBED + col] = f2h(y - h2f(h));
                }
        }
    }
    __syncthreads();   // L4out visible

    // =================== L5: L4 window [64b..) -> X0 (32 rows, swz LDS) ===================
    auto stageA5 = [&](int buf, int t) {     // 4 wave-loads: subtile w&1, w<2 hi else lo
        if (w < 4) {
            const int k0 = t * 32, joff = t >> 3, c = (k0 & 255) + q * 8;
            const int s = w & 1;
            const size_t off = (size_t)(64 * b + 2 * (s * 16 + rr) + joff) * EMBED + c;
            if (w < 2) gload16(L4h + off, &AhT[buf][s * 512]);
            else       gload16(L4l + off, &AlT[buf][s * 512]);
        }
    };
    stageA5(0, 0);
    __syncthreads();   // prologue stage must land before first read
    {
        f32x4 acc[2] = {};
        for (int t = 0; t < 16; ++t, ++g) {
            const int cur = g & 1;
            if (g < 47) stageB(cur ^ 1, ((t + 1) & 15) * 32);
            if (t < 15) stageA5((t + 1) & 1, t + 1);

            const bf16x8 a_h = *(const bf16x8*)&AhT[t & 1][waveM * 512 + l * 8];
            const bf16x8 a_l = *(const bf16x8*)&AlT[t & 1][waveM * 512 + l * 8];
            bf16x8 bh[2], bl[2];
            #pragma unroll
            for (int ni = 0; ni < 2; ++ni) {
                bh[ni] = *(const bf16x8*)&BhT[cur][(waveN * 2 + ni) * 512 + l * 8];
                bl[ni] = *(const bf16x8*)&BlT[cur][(waveN * 2 + ni) * 512 + l * 8];
            }
            #pragma unroll
            for (int ni = 0; ni < 2; ++ni) acc[ni] = MFMA16(a_h, bh[ni], acc[ni]);
            #pragma unroll
            for (int ni = 0; ni < 2; ++ni) acc[ni] = MFMA16(a_l, bh[ni], acc[ni]);
            #pragma unroll
            for (int ni = 0; ni < 2; ++ni) acc[ni] = MFMA16(a_h, bl[ni], acc[ni]);

            __syncthreads();
        }
        #pragma unroll
        for (int ni = 0; ni < 2; ++ni) {
            const int col = waveN * 32 + ni * 16 + rr;
            #pragma unroll
            for (int jj = 0; jj < 4; ++jj) {
                const int row = waveM * 16 + q * 4 + jj;   // 0..31
                const float y = fmaxf(acc[ni][jj] + bv2[ni], 0.f);
                const unsigned short h = f2h(y);
                const int idx = (row * 256 + col) ^ ((row & 7) << 3);
                X0h[idx] = h;
                X0l[idx] = f2h(y - h2f(h));
            }
        }
    }
    __syncthreads();

    // ===== L6..L10: barrier-free direct-register B (16-way N split); A from LDS ping-pong =====
    const float bv1 = bias[w * 16 + rr];

    for (int s = 0; s < 5; ++s) {
        const unsigned short* srch = (s & 1) ? X1h : X0h;
        const unsigned short* srcl = (s & 1) ? X1l : X0l;
        unsigned short* dsth = (s & 1) ? X0h : X1h;
        unsigned short* dstl = (s & 1) ? X0l : X1l;
        const int mask = (s & 1) ? 15 : 31;
        const int Mout = 16 >> s;

        f32x4 acc = {};
        #pragma unroll
        for (int t = 0; t < 16; ++t) {
            const int k0 = t * 32, joff = t >> 3, c = (k0 & 255) + q * 8;
            const int row = (2 * rr + joff) & mask;
            const int idx = (row * 256 + c) ^ ((row & 7) << 3);
            const bf16x8 a_h = *(const bf16x8*)&srch[idx];
            const bf16x8 a_l = *(const bf16x8*)&srcl[idx];

            bf16x8 bh, bl;
            {
                const size_t off = (size_t)(w * 16 + rr) * KDIM + k0 + q * 8;
                if constexpr (WPREP) {
                    bh = *(const bf16x8*)&Wh[off];
                    bl = *(const bf16x8*)&Wl[off];
                } else {
                    const float* ws = Wf + off;
                    float v[8];
                    *(float4*)&v[0] = *(const float4*)ws;
                    *(float4*)&v[4] = *(const float4*)(ws + 4);
                    ushort8 hs, ls;
                    #pragma unroll
                    for (int i = 0; i < 8; ++i) {
                        const unsigned short h = f2h(v[i]);
                        hs[i] = h;
                        ls[i] = f2h(v[i] - h2f(h));
                    }
                    bh = __builtin_bit_cast(bf16x8, hs);
                    bl = __builtin_bit_cast(bf16x8, ls);
                }
            }
            acc = MFMA16(a_h, bh, acc);
            acc = MFMA16(a_l, bh, acc);
            acc = MFMA16(a_h, bl, acc);
        }

        {
            const int col = w * 16 + rr;
            #pragma unroll
            for (int jj = 0; jj < 4; ++jj) {
                const int row = q * 4 + jj;
                if (row < Mout) {
                    const float y = fmaxf(acc[jj] + bv1, 0.f);
                    const unsigned short h = f2h(y);
                    const int idx = (row * 256 + col) ^ ((row & 7) << 3);
                    dsth[idx] = h;
                    dstl[idx] = f2h(y - h2f(h));
                }
            }
        }
        __syncthreads();   // dst complete before next level reads it
    }

    // head: root = X1 row 0 (L10 dst = X1; swizzle identity for row 0)
    if (w == 0) {
        float s0 = 0.f, s1 = 0.f;
        #pragma unroll
        for (int i = 0; i < 4; ++i) {
            const int col = l + i * 64;
            const float x = h2f(X1h[col]) + h2f(X1l[col]);
            s0 = fmaf(x, Pw[col], s0);
            s1 = fmaf(x, Pw[EMBED + col], s1);
        }
        #pragma unroll
        for (int off = 32; off > 0; off >>= 1) {
            s0 += __shfl_down(s0, off);
            s1 += __shfl_down(s1, off);
        }
        if (l == 0) {
            const float l0 = s0 + Pb[0];
            const float l1 = s1 + Pb[1];
            const int pred = (l1 > l0) ? 1 : 0;
            const float m  = fmaxf(l0, l1);
            const float lse = m + logf(expf(l0 - m) + expf(l1 - m));
            const int lab = labels[b];
            out[b]         = (float)pred;
            out[BATCH + b] = lse - (lab ? l1 : l0);
        }
    }
}

extern "C" void kernel_launch(void* const* d_in, const int* in_sizes, int n_in,
                              void* d_out, int out_size, void* d_ws, size_t ws_size,
                              hipStream_t stream)
{
    const int*   token_ids = (const int*)d_in[0];
    const int*   labels    = (const int*)d_in[1];
    const float* emb       = (const float*)d_in[2];
    const float* W_w       = (const float*)d_in[3];
    const float* W_b       = (const float*)d_in[4];
    const float* P_w       = (const float*)d_in[5];
    const float* P_b       = (const float*)d_in[6];
    float*       out       = (float*)d_out;

    // ws layout (ushort units):
    //   Ah/Al: L1 out (131072x256); reused as tail3 scratch (L3out 32768x256 + L4out 16384x256)
    //   Bh/Bl: L2 out (65536x256); hosts pre-split emb tables Eh/El during L1
    //   Wh/Wl: split weights
    unsigned short* Ah_buf = (unsigned short*)d_ws;
    unsigned short* Al_buf = Ah_buf + (size_t)131072 * 256;
    unsigned short* Bh_buf = Al_buf + (size_t)131072 * 256;
    unsigned short* Bl_buf = Bh_buf + (size_t)65536 * 256;
    unsigned short* Wh     = Bl_buf + (size_t)65536 * 256;
    unsigned short* Wl     = Wh + 131072;
    unsigned short* Eh     = Bh_buf;
    unsigned short* El     = Bl_buf;

    const size_t need_wprep = ((size_t)131072 * 256 * 2 + (size_t)65536 * 256 * 2 + 2 * 131072) * 2;
    const bool wprep = ws_size >= need_wprep;

    prep_all<<<6762, 256, 0, stream>>>(emb, Eh, El, W_w, Wh, Wl, wprep ? 1 : 0);

    if (wprep) {
        gemm_tree<1,1><<<1024, 512, 0, stream>>>(nullptr, nullptr, Wh, Wl, W_w, W_b, Ah_buf, Al_buf, token_ids, Eh, El);
        gemm_tree<0,1><<< 512, 512, 0, stream>>>(Ah_buf, Al_buf, Wh, Wl, W_w, W_b, Bh_buf, Bl_buf, nullptr, nullptr, nullptr);
        tail3<1><<<BATCH, 1024, 0, stream>>>(Bh_buf, Bl_buf, Ah_buf, Al_buf, Wh, Wl, W_w, W_b, P_w, P_b, labels, out);
    } else {
        gemm_tree<1,0><<<1024, 512, 0, stream>>>(nullptr, nullptr, Wh, Wl, W_w, W_b, Ah_buf, Al_buf, token_ids, Eh, El);
        gemm_tree<0,0><<< 512, 512, 0, stream>>>(Ah_buf, Al_buf, Wh, Wl, W_w, W_b, Bh_buf, Bl_buf, nullptr, nullptr, nullptr);
        tail3<0><<<BATCH, 1024, 0, stream>>>(Bh_buf, Bl_buf, Ah_buf, Al_buf, Wh, Wl, W_w, W_b, P_w, P_b, labels, out);
    }
}